// Round 6
// baseline (259.391 us; speedup 1.0000x reference)
//
#include <hip/hip_runtime.h>
#include <hip/hip_bf16.h>
#include <stdint.h>

#define E_ 768
#define H_ 768
#define C_ 9
#define M_TOTAL 32768
#define BM_ 64           // tokens per block

typedef __attribute__((ext_vector_type(8))) __bf16 bf16x8;
typedef __attribute__((ext_vector_type(4))) float f32x4;
typedef __attribute__((ext_vector_type(4))) int i32x4;

static_assert(sizeof(bf16x8) == 16, "bf16x8 must be 16B");

__device__ __forceinline__ unsigned short f2bf(float f) {
    __hip_bfloat16 h = __float2bfloat16(f);
    return __builtin_bit_cast(unsigned short, h);
}

// async global->LDS, 16B per lane. lds ptr must be wave-uniform; HW deposits
// lane i's 16B at ldsbase + i*16 (m97-verified width-16 path).
__device__ __forceinline__ void gl_lds16(const unsigned short* g, unsigned short* l) {
    __builtin_amdgcn_global_load_lds(
        (const __attribute__((address_space(1))) uint32_t*)g,
        (__attribute__((address_space(3))) uint32_t*)l, 16, 0, 0);
}

// ---------------------------------------------------------------------------
// Prep: W1 (fp32 [E][H]) -> bf16 B-fragment cells, K-SLICE-MAJOR so each
// BK=32 slice is one contiguous 48 KB block (for global_load_lds streaming):
//   W1f[((t*48 + ntile)*64 + lane)*8 + j] = bf16(W1[k][n])
//     t=k>>5, ntile=n>>4, lane=(n&15)+16*((k>>3)&3), j=k&7
// Block 768 handles W2 -> W2f (B-frag cells padded to 16 cols) + loss zero.
// ---------------------------------------------------------------------------
__global__ void prep_kernel(const float* __restrict__ W1, const float* __restrict__ W2,
                            unsigned short* __restrict__ W1f, unsigned short* __restrict__ W2f,
                            float* __restrict__ loss_out)
{
    int b = blockIdx.x;
    int n = threadIdx.x;
    if (b < 768) {
        int k = b;
        float v = W1[k * H_ + n];
        int ntile = n >> 4;
        int t = k >> 5;
        int lane = (n & 15) + 16 * ((k >> 3) & 3);
        int j = k & 7;
        W1f[((t * 48 + ntile) * 64 + lane) * 8 + j] = f2bf(v);
    } else {
        // W2f: 12288 slots = 16 iters x 768 threads
        for (int it = 0; it < 16; ++it) {
            int tid = it * 768 + n;
            int j    = tid & 7;
            int lane = (tid >> 3) & 63;
            int t    = tid >> 9;
            int cls  = lane & 15;
            int k = t * 32 + (lane >> 4) * 8 + j;
            W2f[tid] = (cls < C_) ? f2bf(W2[k * C_ + cls]) : (unsigned short)0;
        }
        if (n == 0) *loss_out = 0.0f;
    }
}

// ---------------------------------------------------------------------------
// Fused head kernel, round 6 — m97 structure. Block = 64 tokens x full H,
// 8 waves, grid 512, 1 block/CU. Wave = 4 mt x 6 nt, acc[4][6]=96 (AGPR),
// __launch_bounds__(512,2) -> 256-reg budget (R5-verified no-spill).
// KEY CHANGE vs R1/R2/R5 (all flat ~120 us): B comes through LDS via async
// global_load_lds (dbuf 2x48 KB, BK=32 slices), so MFMAs wait only on
// ds_read lgkmcnt (~120cy, compiler fine-grains), never on global vmcnt;
// vmcnt drains only at the per-step barrier under 932 cy of MFMA issue.
// A staged fp32->bf16 via VALU in BK=128 dbuf pieces (2x16 KB), loads on
// substep 0, ds_writes on substep 2 (barrier-covered, never MFMA-blocking).
// LDS = 128 KB (Hsh aliases Bsh[0] in epilogue).
// ---------------------------------------------------------------------------
__launch_bounds__(512, 2)
__global__ void fused_head_kernel(const float* __restrict__ hidden,
                                  const unsigned short* __restrict__ W1f,
                                  const float* __restrict__ b1,
                                  const unsigned short* __restrict__ W2f,
                                  const float* __restrict__ b2,
                                  const int* __restrict__ labels,
                                  const int* __restrict__ epoch_p,
                                  float* __restrict__ probs,
                                  float* __restrict__ loss)
{
    __shared__ unsigned short Bsh[2][24576];   // 2 x 48 KB: B k-slice (48 cells x 1 KB)
    __shared__ unsigned short Asp[2][8192];    // 2 x 16 KB: A piece (BK=128, 16 cells)

    const int tid  = threadIdx.x;
    const int w    = tid >> 6;     // wave 0..7
    const int lane = tid & 63;
    const int tok0 = blockIdx.x * BM_;
    const int c16  = lane & 15;
    const int q    = lane >> 4;

    // ---- A staging invariants (R5 addressing): thread stages u=0..3 ----
    // token = tok0 + u*16 + c16, k = p*128 + (w>>1)*32 + q*8 + (w&1)*4 + 0..3
    const int sg_jb = (w & 1) * 4;
    const float* gbase = hidden + (size_t)(tok0 + c16) * E_ + (w >> 1) * 32 + q * 8 + sg_jb;
    const int lbase = (w >> 1) * 2048 + lane * 8 + sg_jb;

    // ---- B prefetch base: wave w streams its own 6 n-tile cells ----
    const unsigned short* Wg = W1f + (size_t)(w * 6) * 512 + lane * 8;  // + (t*48+i)*512

    // ---- prologue: A piece 0 + async B slice 0 ----
    {
        float4 v[4];
        #pragma unroll
        for (int u = 0; u < 4; ++u) v[u] = *(const float4*)(gbase + u * 16 * E_);
        #pragma unroll
        for (int u = 0; u < 4; ++u) {
            ushort4 pk = { f2bf(v[u].x), f2bf(v[u].y), f2bf(v[u].z), f2bf(v[u].w) };
            *(ushort4*)(&Asp[0][lbase + u * 512]) = pk;
        }
    }
    #pragma unroll
    for (int i = 0; i < 6; ++i)
        gl_lds16(Wg + (size_t)i * 512, &Bsh[0][(w * 6 + i) * 512]);
    __syncthreads();   // drains vmcnt (B slice 0) + lgkm (A piece 0)

    const f32x4 zero4 = {0.0f, 0.0f, 0.0f, 0.0f};
    f32x4 acc[4][6];
    #pragma unroll
    for (int mt = 0; mt < 4; ++mt)
        #pragma unroll
        for (int nt = 0; nt < 6; ++nt) acc[mt][nt] = zero4;

    // compute k-step t: A from Asp[p&1], B from Bsh[x&1] (x = t&3; 4p even)
#define CSTEP(Ab, Bb, x)                                                             \
    {                                                                                \
        bf16x8 bfr[6];                                                               \
        _Pragma("unroll")                                                            \
        for (int nt = 0; nt < 6; ++nt)                                               \
            bfr[nt] = __builtin_bit_cast(bf16x8,                                     \
                *(const i32x4*)(&(Bb)[((w * 6 + nt) * 64 + lane) * 8]));             \
        _Pragma("unroll")                                                            \
        for (int mt = 0; mt < 4; ++mt) {                                             \
            bf16x8 af = __builtin_bit_cast(bf16x8,                                   \
                *(const i32x4*)(&(Ab)[(((x) * 4 + mt) * 512) + lane * 8]));          \
            _Pragma("unroll")                                                        \
            for (int nt = 0; nt < 6; ++nt)                                           \
                acc[mt][nt] = __builtin_amdgcn_mfma_f32_16x16x32_bf16(               \
                    af, bfr[nt], acc[mt][nt], 0, 0, 0);                              \
        }                                                                            \
    }

#define BPREF(tn)                                                                    \
    {                                                                                \
        _Pragma("unroll")                                                            \
        for (int i = 0; i < 6; ++i)                                                  \
            gl_lds16(Wg + ((size_t)(tn) * 48 + i) * 512,                             \
                     &Bsh[(tn) & 1][(w * 6 + i) * 512]);                             \
    }

    // ---- K loop: 6 pieces x 4 k-steps, B dbuf per step, A dbuf per piece ----
    for (int p = 0; p < 6; ++p) {
        const unsigned short* Ab = &Asp[p & 1][0];
        unsigned short* An = &Asp[(p + 1) & 1][0];
        const bool pf = (p < 5);
        float4 v[4];
        // substep 0 (t=4p, B buf 0): prefetch B t+1 -> buf1; load next A fp32
        BPREF(4 * p + 1)
        if (pf) {
            #pragma unroll
            for (int u = 0; u < 4; ++u)
                v[u] = *(const float4*)(gbase + (p + 1) * 128 + u * 16 * E_);
        }
        CSTEP(Ab, Bsh[0], 0)
        __syncthreads();
        // substep 1 (t=4p+1, B buf 1): prefetch B t+1 -> buf0
        BPREF(4 * p + 2)
        CSTEP(Ab, Bsh[1], 1)
        __syncthreads();
        // substep 2 (t=4p+2, B buf 0): prefetch B t+1 -> buf1; ds_write next A
        BPREF(4 * p + 3)
        if (pf) {
            #pragma unroll
            for (int u = 0; u < 4; ++u) {
                ushort4 pk = { f2bf(v[u].x), f2bf(v[u].y), f2bf(v[u].z), f2bf(v[u].w) };
                *(ushort4*)(&An[lbase + u * 512]) = pk;
            }
        }
        CSTEP(Ab, Bsh[0], 2)
        __syncthreads();
        // substep 3 (t=4p+3, B buf 1): prefetch B t+1 -> buf0 (unless last)
        if (p < 5) BPREF(4 * p + 4)
        CSTEP(Ab, Bsh[1], 3)
        __syncthreads();
    }
#undef CSTEP
#undef BPREF

    // ---- epilogue: Hsh aliases Bsh[0] (B dead now; last barrier covers it) ----
    unsigned short* Hsh = &Bsh[0][0];   // 24 KB used of 48
    f32x4 logit = zero4;   // waves 0-3: logits for rows w*16..w*16+15
    const int myc = w >> 1;
    for (int c = 0; c < 4; ++c) {
        if (myc == c) {
            #pragma unroll
            for (int i = 0; i < 6; ++i) {
                int kloc = (w & 1) * 96 + i * 16 + c16;    // phase-local h-col 0..191
                float b1v = b1[w * 96 + i * 16 + c16];     // global col = c*192 + kloc
                int t2 = kloc >> 5;
                int q2 = (kloc >> 3) & 3;
                int j  = kloc & 7;
                #pragma unroll
                for (int mt = 0; mt < 4; ++mt) {
                    #pragma unroll
                    for (int r = 0; r < 4; ++r) {
                        float z = acc[mt][i][r] + b1v;
                        // tanh(z) = 1 - 2/(exp(2z)+1), exp via native exp2
                        float e = exp2f(z * 2.8853900817779268f);
                        float th = 1.0f - 2.0f * __builtin_amdgcn_rcpf(e + 1.0f);
                        int lanep = (q * 4 + r) + 16 * q2;  // frag lane for row mt*16+q*4+r
                        Hsh[((t2 * 4 + mt) * 64 + lanep) * 8 + j] = f2bf(th);
                    }
                }
            }
        }
        __syncthreads();   // h phase visible
        if (w < 4) {
            #pragma unroll
            for (int t2 = 0; t2 < 6; ++t2) {
                bf16x8 ha = __builtin_bit_cast(bf16x8, *(const i32x4*)(&Hsh[((t2 * 4 + w) * 64 + lane) * 8]));
                bf16x8 wb = __builtin_bit_cast(bf16x8, *(const i32x4*)(W2f + ((size_t)(c * 6 + t2) * 64 + lane) * 8));
                logit = __builtin_amdgcn_mfma_f32_16x16x32_bf16(ha, wb, logit, 0, 0, 0);
            }
        }
        __syncthreads();   // logit reads done before next phase rewrites Hsh
    }

    // ---- softmax over 9 classes (16-lane groups), probs store, loss ----
    if (w < 4) {
        const bool valid = (c16 < C_);
        const float b2v = valid ? b2[c16] : 0.0f;
        const int ep = epoch_p[0];
        float lsum = 0.0f;
        #pragma unroll
        for (int r = 0; r < 4; ++r) {
            float l = valid ? (logit[r] + b2v) : -3.0e38f;
            float m = l;
            #pragma unroll
            for (int d = 1; d < 16; d <<= 1)
                m = fmaxf(m, __shfl_xor(m, d, 64));
            float e = valid ? exp2f((l - m) * 1.44269504f) : 0.0f;
            float s = e;
            #pragma unroll
            for (int d = 1; d < 16; d <<= 1)
                s += __shfl_xor(s, d, 64);
            float p = e / s;
            int row = tok0 + w * 16 + q * 4 + r;
            if (valid) probs[(size_t)row * C_ + c16] = p;
            int lab = labels[row];
            if (valid && lab == c16) {
                float wgt = (ep <= 2) ? 1.0f : ((p > 0.7f) ? 1.0f : 0.0f);
                if (wgt > 0.0f)
                    lsum += (1.0f - exp2f(0.7f * log2f(p))) * (1.0f / 0.7f);
            }
        }
        #pragma unroll
        for (int d = 1; d < 64; d <<= 1)
            lsum += __shfl_xor(lsum, d, 64);
        if (lane == 0) atomicAdd(loss, lsum);
    }
}

// ---------------------------------------------------------------------------
extern "C" void kernel_launch(void* const* d_in, const int* in_sizes, int n_in,
                              void* d_out, int out_size, void* d_ws, size_t ws_size,
                              hipStream_t stream)
{
    const float* hidden = (const float*)d_in[0];
    const float* W1     = (const float*)d_in[1];
    const float* b1     = (const float*)d_in[2];
    const float* W2     = (const float*)d_in[3];
    const float* b2     = (const float*)d_in[4];
    const int*   labels = (const int*)d_in[5];
    const int*   epoch  = (const int*)d_in[6];

    float* probs = (float*)d_out;                       // [32768 x 9]
    float* loss  = probs + (size_t)M_TOTAL * C_;        // scalar at the end

    unsigned short* W1f = (unsigned short*)d_ws;        // 589824 bf16 (k-slice-major)
    unsigned short* W2f = W1f + 24 * 48 * 512;          // 12288 bf16

    prep_kernel<<<769, 768, 0, stream>>>(W1, W2, W1f, W2f, loss);
    fused_head_kernel<<<M_TOTAL / BM_, 512, 0, stream>>>(hidden, W1f, b1, W2f, b2,
                                                         labels, epoch, probs, loss);
}

// Round 7
// 224.330 us; speedup vs baseline: 1.1563x; 1.1563x over previous
//
#include <hip/hip_runtime.h>
#include <hip/hip_bf16.h>
#include <stdint.h>

#define E_ 768
#define H_ 768
#define C_ 9
#define M_TOTAL 32768
#define BM_ 64           // tokens per block

typedef __attribute__((ext_vector_type(8))) __bf16 bf16x8;
typedef __attribute__((ext_vector_type(4))) float f32x4;
typedef __attribute__((ext_vector_type(4))) int i32x4;

static_assert(sizeof(bf16x8) == 16, "bf16x8 must be 16B");

__device__ __forceinline__ unsigned short f2bf(float f) {
    __hip_bfloat16 h = __float2bfloat16(f);
    return __builtin_bit_cast(unsigned short, h);
}

// ---------------------------------------------------------------------------
// Prep (R5 layout): W1 (fp32 [E][H]) -> bf16 B-fragment cells, ntile-major:
//   W1f[((ntile*24 + t)*64 + lane)*8 + j] = bf16(W1[k][n])
//     ntile=n>>4, t=k>>5, lane=(n&15)+16*((k>>3)&3), j=k&7
// Block 768 handles W2 -> W2f (B-frag cells padded to 16 cols) + loss zero.
// ---------------------------------------------------------------------------
__global__ void prep_kernel(const float* __restrict__ W1, const float* __restrict__ W2,
                            unsigned short* __restrict__ W1f, unsigned short* __restrict__ W2f,
                            float* __restrict__ loss_out)
{
    int b = blockIdx.x;
    int n = threadIdx.x;
    if (b < 768) {
        int k = b;
        float v = W1[k * H_ + n];
        int ntile = n >> 4;
        int t = k >> 5;
        int lane = (n & 15) + 16 * ((k >> 3) & 3);
        int j = k & 7;
        W1f[((ntile * 24 + t) * 64 + lane) * 8 + j] = f2bf(v);
    } else {
        for (int it = 0; it < 16; ++it) {
            int tid = it * 768 + n;
            int j    = tid & 7;
            int lane = (tid >> 3) & 63;
            int t    = tid >> 9;
            int cls  = lane & 15;
            int k = t * 32 + (lane >> 4) * 8 + j;
            W2f[tid] = (cls < C_) ? f2bf(W2[k * C_ + cls]) : (unsigned short)0;
        }
        if (n == 0) *loss_out = 0.0f;
    }
}

// ---------------------------------------------------------------------------
// Fused head kernel, round 7. Block = 64 tokens x full H=768, SIXTEEN waves
// (1024 thr) -> 4 waves/SIMD (R1-R6 were stuck at 1-2 waves/SIMD, ~12%
// MfmaUtil, ~1700 cyc/k-step constant idle). Wave owns 4 mt x 3 nt ->
// acc[4][3] = 48 f32; total regs ~115 <= 128 @ __launch_bounds__(1024,4).
// A (hidden) fp32->bf16 frag cells staged ONCE in 96 KB LDS, loaded with
// NONTEMPORAL hints (stop evicting W1f from the 4 MB/XCD L2 - suspected
// source of ~900-cyc B-miss stalls). K-loop barrier-free, B register-direct
// from W1f with explicit distance-2 double-rotation prefetch (bA/bB) so
// even L2-miss latency is covered by in-flight time.
// Epilogue: Hsh aliases Ash; 4 phases of 192 cols (waves 4c..4c+3 tanh),
// waves 0-3 logit-MFMA + softmax + probs + loss.
// ---------------------------------------------------------------------------
__launch_bounds__(1024, 4)
__global__ void fused_head_kernel(const float* __restrict__ hidden,
                                  const unsigned short* __restrict__ W1f,
                                  const float* __restrict__ b1,
                                  const unsigned short* __restrict__ W2f,
                                  const float* __restrict__ b2,
                                  const int* __restrict__ labels,
                                  const int* __restrict__ epoch_p,
                                  float* __restrict__ probs,
                                  float* __restrict__ loss)
{
    __shared__ unsigned short Ash[24 * 4 * 512];   // 96 KB: A frag cells [t][mt][lane*8]

    const int tid  = threadIdx.x;
    const int w    = tid >> 6;     // wave 0..15
    const int lane = tid & 63;
    const int tok0 = blockIdx.x * BM_;
    const int c16  = lane & 15;
    const int q    = lane >> 4;

    // ---- stage A once: 64 rows x 192 float4, nontemporal, fp32->bf16 ----
    {
        const f32x4* hsrc = (const f32x4*)(hidden + (size_t)tok0 * E_);
        #pragma unroll
        for (int i = 0; i < 12; ++i) {
            int slot = i * 1024 + tid;
            int tk = slot / 192;           // token row 0..63
            int fq = slot - tk * 192;      // float4 index in row
            f32x4 v = __builtin_nontemporal_load(hsrc + (size_t)tk * 192 + fq);
            int k = fq * 4;
            int t = k >> 5, mt = tk >> 4;
            int lnf = (tk & 15) + 16 * ((k >> 3) & 3);
            int j = k & 7;                 // 0 or 4
            ushort4 pk = { f2bf(v[0]), f2bf(v[1]), f2bf(v[2]), f2bf(v[3]) };
            *(ushort4*)(&Ash[((t * 4 + mt) * 64 + lnf) * 8 + j]) = pk;
        }
    }
    __syncthreads();

    // ---- K loop: barrier-free, B register-direct w/ distance-2 prefetch ----
    const unsigned short* Wp = W1f + (size_t)(w * 3 * 24) * 512 + lane * 8;

    bf16x8 bA[3], bB[3];
    #pragma unroll
    for (int i = 0; i < 3; ++i)
        bA[i] = __builtin_bit_cast(bf16x8, *(const i32x4*)(Wp + (i * 24 + 0) * 512));
    #pragma unroll
    for (int i = 0; i < 3; ++i)
        bB[i] = __builtin_bit_cast(bf16x8, *(const i32x4*)(Wp + (i * 24 + 1) * 512));

    const f32x4 zero4 = {0.0f, 0.0f, 0.0f, 0.0f};
    f32x4 acc[4][3];
    #pragma unroll
    for (int mt = 0; mt < 4; ++mt)
        #pragma unroll
        for (int nt = 0; nt < 3; ++nt) acc[mt][nt] = zero4;

    #pragma unroll
    for (int tt = 0; tt < 12; ++tt) {
        // even k-step t0 = 2tt: consume bA
        {
            bf16x8 af[4];
            #pragma unroll
            for (int mt = 0; mt < 4; ++mt)
                af[mt] = __builtin_bit_cast(bf16x8,
                    *(const i32x4*)(&Ash[(((2 * tt) * 4 + mt) * 64 + lane) * 8]));
            #pragma unroll
            for (int mt = 0; mt < 4; ++mt)
                #pragma unroll
                for (int nt = 0; nt < 3; ++nt)
                    acc[mt][nt] = __builtin_amdgcn_mfma_f32_16x16x32_bf16(
                        af[mt], bA[nt], acc[mt][nt], 0, 0, 0);
        }
        if (tt < 11) {
            #pragma unroll
            for (int i = 0; i < 3; ++i)
                bA[i] = __builtin_bit_cast(bf16x8,
                    *(const i32x4*)(Wp + (i * 24 + 2 * tt + 2) * 512));
        }
        // odd k-step t1 = 2tt+1: consume bB
        {
            bf16x8 af[4];
            #pragma unroll
            for (int mt = 0; mt < 4; ++mt)
                af[mt] = __builtin_bit_cast(bf16x8,
                    *(const i32x4*)(&Ash[(((2 * tt + 1) * 4 + mt) * 64 + lane) * 8]));
            #pragma unroll
            for (int mt = 0; mt < 4; ++mt)
                #pragma unroll
                for (int nt = 0; nt < 3; ++nt)
                    acc[mt][nt] = __builtin_amdgcn_mfma_f32_16x16x32_bf16(
                        af[mt], bB[nt], acc[mt][nt], 0, 0, 0);
        }
        if (tt < 11) {
            #pragma unroll
            for (int i = 0; i < 3; ++i)
                bB[i] = __builtin_bit_cast(bf16x8,
                    *(const i32x4*)(Wp + (i * 24 + 2 * tt + 3) * 512));
        }
    }
    __syncthreads();   // K-loop done on ALL waves before Ash is reused as Hsh

    // ---- epilogue: Hsh aliases Ash. 4 phases of 192 cols. ----
    unsigned short* Hsh = &Ash[0];   // 24 KB used of 96
    f32x4 logit = zero4;             // waves 0-3: logits for rows w*16..w*16+15
    const int myc = w >> 2;
    for (int c = 0; c < 4; ++c) {
        if (myc == c) {              // waves 4c..4c+3 write their 48-col slices
            #pragma unroll
            for (int i = 0; i < 3; ++i) {
                int kloc = (w & 3) * 48 + i * 16 + c16;    // phase-local h-col 0..191
                float b1v = b1[w * 48 + i * 16 + c16];     // global col
                int t2 = kloc >> 5;
                int q2 = (kloc >> 3) & 3;
                int j  = kloc & 7;
                #pragma unroll
                for (int mt = 0; mt < 4; ++mt) {
                    #pragma unroll
                    for (int r = 0; r < 4; ++r) {
                        float z = acc[mt][i][r] + b1v;
                        // tanh(z) = 1 - 2/(exp(2z)+1), exp via native exp2
                        float e = exp2f(z * 2.8853900817779268f);
                        float th = 1.0f - 2.0f * __builtin_amdgcn_rcpf(e + 1.0f);
                        int lanep = (q * 4 + r) + 16 * q2;  // frag lane for row mt*16+q*4+r
                        Hsh[((t2 * 4 + mt) * 64 + lanep) * 8 + j] = f2bf(th);
                    }
                }
            }
        }
        __syncthreads();   // h phase visible
        if (w < 4) {
            #pragma unroll
            for (int t2 = 0; t2 < 6; ++t2) {
                bf16x8 ha = __builtin_bit_cast(bf16x8, *(const i32x4*)(&Hsh[((t2 * 4 + w) * 64 + lane) * 8]));
                bf16x8 wb = __builtin_bit_cast(bf16x8, *(const i32x4*)(W2f + ((size_t)(c * 6 + t2) * 64 + lane) * 8));
                logit = __builtin_amdgcn_mfma_f32_16x16x32_bf16(ha, wb, logit, 0, 0, 0);
            }
        }
        __syncthreads();   // logit reads done before next phase rewrites Hsh
    }

    // ---- softmax over 9 classes (16-lane groups), probs store, loss ----
    if (w < 4) {
        const bool valid = (c16 < C_);
        const float b2v = valid ? b2[c16] : 0.0f;
        const int ep = epoch_p[0];
        float lsum = 0.0f;
        #pragma unroll
        for (int r = 0; r < 4; ++r) {
            float l = valid ? (logit[r] + b2v) : -3.0e38f;
            float m = l;
            #pragma unroll
            for (int d = 1; d < 16; d <<= 1)
                m = fmaxf(m, __shfl_xor(m, d, 64));
            float e = valid ? exp2f((l - m) * 1.44269504f) : 0.0f;
            float s = e;
            #pragma unroll
            for (int d = 1; d < 16; d <<= 1)
                s += __shfl_xor(s, d, 64);
            float p = e / s;
            int row = tok0 + w * 16 + q * 4 + r;
            if (valid) probs[(size_t)row * C_ + c16] = p;
            int lab = labels[row];
            if (valid && lab == c16) {
                float wgt = (ep <= 2) ? 1.0f : ((p > 0.7f) ? 1.0f : 0.0f);
                if (wgt > 0.0f)
                    lsum += (1.0f - exp2f(0.7f * log2f(p))) * (1.0f / 0.7f);
            }
        }
        #pragma unroll
        for (int d = 1; d < 64; d <<= 1)
            lsum += __shfl_xor(lsum, d, 64);
        if (lane == 0) atomicAdd(loss, lsum);
    }
}

// ---------------------------------------------------------------------------
extern "C" void kernel_launch(void* const* d_in, const int* in_sizes, int n_in,
                              void* d_out, int out_size, void* d_ws, size_t ws_size,
                              hipStream_t stream)
{
    const float* hidden = (const float*)d_in[0];
    const float* W1     = (const float*)d_in[1];
    const float* b1     = (const float*)d_in[2];
    const float* W2     = (const float*)d_in[3];
    const float* b2     = (const float*)d_in[4];
    const int*   labels = (const int*)d_in[5];
    const int*   epoch  = (const int*)d_in[6];

    float* probs = (float*)d_out;                       // [32768 x 9]
    float* loss  = probs + (size_t)M_TOTAL * C_;        // scalar at the end

    unsigned short* W1f = (unsigned short*)d_ws;        // 589824 bf16 (ntile-major)
    unsigned short* W2f = W1f + 48 * 24 * 512;          // 12288 bf16

    prep_kernel<<<769, 768, 0, stream>>>(W1, W2, W1f, W2f, loss);
    fused_head_kernel<<<M_TOTAL / BM_, 1024, 0, stream>>>(hidden, W1f, b1, W2f, b2,
                                                          labels, epoch, probs, loss);
}